// Round 1
// baseline (311.370 us; speedup 1.0000x reference)
//
#include <hip/hip_runtime.h>
#include <hip/hip_bf16.h>

#define D 128
#define NH 4
#define NEG_SLOPE 0.2f
#define LN_EPS 1e-5f

__device__ __forceinline__ float bf2f(unsigned short u) {
  union { unsigned int i; float f; } c; c.i = ((unsigned int)u) << 16; return c.f;
}
__device__ __forceinline__ unsigned short f2bf(float f) {
  union { float f; unsigned int i; } c; c.f = f;
  unsigned int r = c.i + 0x7FFFu + ((c.i >> 16) & 1u);  // RNE
  return (unsigned short)(r >> 16);
}

// ---------------- GEMM: X @ [W_gat(h=0..3) | W_gcn] -> xh (bf16), xg (bf16) ----
__global__ __launch_bounds__(256) void k_gemm(
    const float* __restrict__ x, const float* __restrict__ Wgat,
    const float* __restrict__ Wgcn,
    unsigned short* __restrict__ xh, unsigned short* __restrict__ xg, int N)
{
  __shared__ float As[64][68];   // [k][m], padded: 272B rows, 16B-aligned frags
  __shared__ float Bs[64][64];   // [k][n]
  const int t = threadIdx.x;
  const int tx = t & 15, ty = t >> 4;
  const int m0 = blockIdx.x * 64;

  for (int ct = 0; ct < 10; ++ct) {
    const float* Bbase; int f0;
    if (ct < 8) { int h = ct >> 1; f0 = (ct & 1) * 64; Bbase = Wgat + h * D * D + f0; }
    else        { f0 = (ct - 8) * 64;                  Bbase = Wgcn + f0; }

    float acc[4][4];
    #pragma unroll
    for (int i = 0; i < 4; ++i)
      #pragma unroll
      for (int j = 0; j < 4; ++j) acc[i][j] = 0.f;

    for (int kt = 0; kt < 2; ++kt) {
      const int k0 = kt * 64;
      __syncthreads();
      #pragma unroll
      for (int i = 0; i < 16; ++i) {
        int idx = i * 256 + t;
        int k = idx & 63, m = idx >> 6;
        int gm = m0 + m;
        As[k][m] = (gm < N) ? x[(size_t)gm * D + k0 + k] : 0.f;
      }
      #pragma unroll
      for (int i = 0; i < 16; ++i) {
        int idx = i * 256 + t;
        int n = idx & 63, k = idx >> 6;
        Bs[k][n] = Bbase[(size_t)(k0 + k) * D + n];
      }
      __syncthreads();
      #pragma unroll
      for (int k = 0; k < 64; ++k) {
        float4 a = *(const float4*)&As[k][ty * 4];
        float4 b = *(const float4*)&Bs[k][tx * 4];
        float av[4] = {a.x, a.y, a.z, a.w};
        float bv[4] = {b.x, b.y, b.z, b.w};
        #pragma unroll
        for (int i = 0; i < 4; ++i)
          #pragma unroll
          for (int j = 0; j < 4; ++j) acc[i][j] += av[i] * bv[j];
      }
    }
    #pragma unroll
    for (int i = 0; i < 4; ++i) {
      int gm = m0 + ty * 4 + i;
      if (gm >= N) continue;
      ushort4 pk;
      pk.x = f2bf(acc[i][0]); pk.y = f2bf(acc[i][1]);
      pk.z = f2bf(acc[i][2]); pk.w = f2bf(acc[i][3]);
      int f = f0 + tx * 4;
      if (ct < 8) {
        int h = ct >> 1;
        *(ushort4*)&xh[((size_t)gm * NH + h) * D + f] = pk;
      } else {
        *(ushort4*)&xg[(size_t)gm * D + f] = pk;
      }
    }
  }
}

// ---------------- per-node attention dots: a_s[n,h], a_d[n,h] -------------------
__global__ __launch_bounds__(256) void k_att(
    const unsigned short* __restrict__ xh,
    const float* __restrict__ att_src, const float* __restrict__ att_dst,
    float* __restrict__ a_s, float* __restrict__ a_d, int N)
{
  int n = blockIdx.x;
  int h = threadIdx.x >> 6;
  int l = threadIdx.x & 63;
  const unsigned short* row = xh + ((size_t)n * NH + h) * D;
  float v0 = bf2f(row[l]), v1 = bf2f(row[l + 64]);
  float s = v0 * att_src[h * D + l] + v1 * att_src[h * D + l + 64];
  float d = v0 * att_dst[h * D + l] + v1 * att_dst[h * D + l + 64];
  #pragma unroll
  for (int off = 32; off; off >>= 1) { s += __shfl_xor(s, off); d += __shfl_xor(d, off); }
  if (l == 0) { a_s[n * NH + h] = s; a_d[n * NH + h] = d; }
}

// ---------------- CSR build ----------------------------------------------------
__global__ void k_deg(const int* __restrict__ ei, int E, int N, int* __restrict__ deg)
{
  int e = blockIdx.x * blockDim.x + threadIdx.x;
  if (e >= E + N) return;
  int dst = (e < E) ? ei[E + e] : (e - E);
  atomicAdd(&deg[dst], 1);
}

__global__ void k_scan1(const int* __restrict__ deg, int N, int* __restrict__ bsum)
{
  __shared__ int s[256];
  int t = threadIdx.x;
  int i = blockIdx.x * 256 + t;
  s[t] = (i < N) ? deg[i] : 0;
  __syncthreads();
  for (int off = 128; off; off >>= 1) {
    if (t < off) s[t] += s[t + off];
    __syncthreads();
  }
  if (t == 0) bsum[blockIdx.x] = s[0];
}

__global__ void k_scan2(int* __restrict__ bsum, int nb)
{
  __shared__ int s[128];
  int t = threadIdx.x;
  int v = (t < nb) ? bsum[t] : 0;
  s[t] = v; __syncthreads();
  for (int off = 1; off < 128; off <<= 1) {
    int xv = (t >= off) ? s[t - off] : 0;
    __syncthreads();
    s[t] += xv;
    __syncthreads();
  }
  if (t < nb) bsum[t] = s[t] - v;   // exclusive
}

__global__ void k_scan3(const int* __restrict__ deg, const int* __restrict__ bsum,
                        int N, int Et, int* __restrict__ row_ptr,
                        int* __restrict__ cursor, float* __restrict__ dinv)
{
  __shared__ int s[256];
  int t = threadIdx.x;
  int i = blockIdx.x * 256 + t;
  int v = (i < N) ? deg[i] : 0;
  s[t] = v; __syncthreads();
  for (int off = 1; off < 256; off <<= 1) {
    int xv = (t >= off) ? s[t - off] : 0;
    __syncthreads();
    s[t] += xv;
    __syncthreads();
  }
  if (i < N) {
    int excl = s[t] - v + bsum[blockIdx.x];
    row_ptr[i] = excl;
    cursor[i] = excl;
    dinv[i] = rsqrtf((float)v);    // deg >= 1 (self-loop)
  }
  if (i == 0) row_ptr[N] = Et;
}

__global__ void k_fill(const int* __restrict__ ei, int E, int N,
                       int* __restrict__ cursor, int* __restrict__ col_src)
{
  int e = blockIdx.x * blockDim.x + threadIdx.x;
  if (e >= E + N) return;
  int src, dst;
  if (e < E) { src = ei[e]; dst = ei[E + e]; }
  else       { src = e - E; dst = src; }
  int pos = atomicAdd(&cursor[dst], 1);
  col_src[pos] = src;
}

// ---------------- aggregation: one wave per node, softmax + GAT + GCN ----------
__global__ __launch_bounds__(256) void k_agg(
    const unsigned short* __restrict__ xh, const unsigned short* __restrict__ xg,
    const float* __restrict__ a_s, const float* __restrict__ a_d,
    const int* __restrict__ row_ptr, const int* __restrict__ col_src,
    const float* __restrict__ dinv,
    float* __restrict__ gat_acc, float* __restrict__ gcn_acc, int N)
{
  int n = blockIdx.x * 4 + (threadIdx.x >> 6);
  if (n >= N) return;
  int l = threadIdx.x & 63;
  int start = row_ptr[n], end = row_ptr[n + 1];
  float4 adn = ((const float4*)a_d)[n];

  // pass 1: softmax denominators (edges parallel over lanes)
  float den0 = 0.f, den1 = 0.f, den2 = 0.f, den3 = 0.f;
  for (int base = start; base < end; base += 64) {
    int e = base + l;
    if (e < end) {
      int s = col_src[e];
      float4 as4 = ((const float4*)a_s)[s];
      float e0 = as4.x + adn.x; e0 = (e0 >= 0.f) ? e0 : NEG_SLOPE * e0;
      float e1 = as4.y + adn.y; e1 = (e1 >= 0.f) ? e1 : NEG_SLOPE * e1;
      float e2 = as4.z + adn.z; e2 = (e2 >= 0.f) ? e2 : NEG_SLOPE * e2;
      float e3 = as4.w + adn.w; e3 = (e3 >= 0.f) ? e3 : NEG_SLOPE * e3;
      den0 += __expf(e0); den1 += __expf(e1);
      den2 += __expf(e2); den3 += __expf(e3);
    }
  }
  #pragma unroll
  for (int off = 32; off; off >>= 1) {
    den0 += __shfl_xor(den0, off); den1 += __shfl_xor(den1, off);
    den2 += __shfl_xor(den2, off); den3 += __shfl_xor(den3, off);
  }
  const float r0 = 1.f / den0, r1 = 1.f / den1, r2 = 1.f / den2, r3 = 1.f / den3;
  const float dn = dinv[n];

  // pass 2: weighted aggregation, lane l owns dims {2l, 2l+1}
  float gx = 0.f, gy = 0.f, cx = 0.f, cy = 0.f;
  const ushort2* xh2 = (const ushort2*)xh;
  const ushort2* xg2 = (const ushort2*)xg;
  for (int e = start; e < end; ++e) {
    int s = col_src[e];
    float4 as4 = ((const float4*)a_s)[s];
    float e0 = as4.x + adn.x; e0 = (e0 >= 0.f) ? e0 : NEG_SLOPE * e0;
    float e1 = as4.y + adn.y; e1 = (e1 >= 0.f) ? e1 : NEG_SLOPE * e1;
    float e2 = as4.z + adn.z; e2 = (e2 >= 0.f) ? e2 : NEG_SLOPE * e2;
    float e3 = as4.w + adn.w; e3 = (e3 >= 0.f) ? e3 : NEG_SLOPE * e3;
    float a0 = __expf(e0) * r0, a1 = __expf(e1) * r1;
    float a2 = __expf(e2) * r2, a3 = __expf(e3) * r3;
    float coef = dn * dinv[s];
    size_t rb = (size_t)s * 256 + l;     // ushort2 index, head stride 64
    ushort2 v0 = xh2[rb];
    ushort2 v1 = xh2[rb + 64];
    ushort2 v2 = xh2[rb + 128];
    ushort2 v3 = xh2[rb + 192];
    gx += a0 * bf2f(v0.x) + a1 * bf2f(v1.x) + a2 * bf2f(v2.x) + a3 * bf2f(v3.x);
    gy += a0 * bf2f(v0.y) + a1 * bf2f(v1.y) + a2 * bf2f(v2.y) + a3 * bf2f(v3.y);
    ushort2 vg = xg2[(size_t)s * 64 + l];
    cx += coef * bf2f(vg.x);
    cy += coef * bf2f(vg.y);
  }
  ((float2*)gat_acc)[(size_t)n * 64 + l] = make_float2(gx, gy);
  ((float2*)gcn_acc)[(size_t)n * 64 + l] = make_float2(cx, cy);
}

// ---------------- gate + residual + LayerNorm ----------------------------------
__global__ __launch_bounds__(256) void k_final(
    const float* __restrict__ gat_acc, const float* __restrict__ gcn_acc,
    const float* __restrict__ b_gat, const float* __restrict__ b_gcn,
    const float* __restrict__ W_gate, const float* __restrict__ b_gate,
    const float* __restrict__ gamma, const float* __restrict__ beta,
    float* __restrict__ out, int N)
{
  int n = blockIdx.x * 4 + (threadIdx.x >> 6);
  if (n >= N) return;
  int l = threadIdx.x & 63;
  float2 ga = ((const float2*)gat_acc)[(size_t)n * 64 + l];
  float2 gc = ((const float2*)gcn_acc)[(size_t)n * 64 + l];
  float2 bg = ((const float2*)b_gat)[l];
  float2 bc = ((const float2*)b_gcn)[l];
  float g0x = ga.x * 0.25f + bg.x, g0y = ga.y * 0.25f + bg.y;
  float c0x = gc.x + bc.x,         c0y = gc.y + bc.y;
  float4 wa = ((const float4*)W_gate)[l];        // rows 2l, 2l+1
  float4 wc = ((const float4*)W_gate)[64 + l];   // rows 128+2l, 128+2l+1
  float z0 = g0x * wa.x + g0y * wa.z + c0x * wc.x + c0y * wc.z;
  float z1 = g0x * wa.y + g0y * wa.w + c0x * wc.y + c0y * wc.w;
  #pragma unroll
  for (int off = 32; off; off >>= 1) { z0 += __shfl_xor(z0, off); z1 += __shfl_xor(z1, off); }
  z0 += b_gate[0]; z1 += b_gate[1];
  float mz = fmaxf(z0, z1);
  float ez0 = __expf(z0 - mz), ez1 = __expf(z1 - mz);
  float inv = 1.f / (ez0 + ez1);
  float w0 = ez0 * inv, w1 = ez1 * inv;
  float hx = (1.f + w0) * g0x + w1 * c0x;   // fused + gat_out
  float hy = (1.f + w0) * g0y + w1 * c0y;
  float ssum = hx + hy;
  #pragma unroll
  for (int off = 32; off; off >>= 1) ssum += __shfl_xor(ssum, off);
  float mu = ssum * (1.f / 128.f);
  float vx = hx - mu, vy = hy - mu;
  float vsum = vx * vx + vy * vy;
  #pragma unroll
  for (int off = 32; off; off >>= 1) vsum += __shfl_xor(vsum, off);
  float rstd = rsqrtf(vsum * (1.f / 128.f) + LN_EPS);
  float2 gm = ((const float2*)gamma)[l];
  float2 bt = ((const float2*)beta)[l];
  float2 o;
  o.x = vx * rstd * gm.x + bt.x;
  o.y = vy * rstd * gm.y + bt.y;
  ((float2*)out)[(size_t)n * 64 + l] = o;
}

extern "C" void kernel_launch(void* const* d_in, const int* in_sizes, int n_in,
                              void* d_out, int out_size, void* d_ws, size_t ws_size,
                              hipStream_t stream)
{
  const float* x       = (const float*)d_in[0];
  const int*   ei      = (const int*)d_in[1];
  const float* Wgat    = (const float*)d_in[2];
  const float* att_src = (const float*)d_in[3];
  const float* att_dst = (const float*)d_in[4];
  const float* b_gat   = (const float*)d_in[5];
  const float* Wgcn    = (const float*)d_in[6];
  const float* b_gcn   = (const float*)d_in[7];
  const float* W_gate  = (const float*)d_in[8];
  const float* b_gate  = (const float*)d_in[9];
  const float* gamma   = (const float*)d_in[10];
  const float* beta    = (const float*)d_in[11];
  float* out = (float*)d_out;

  const int N  = in_sizes[0] / D;   // 30000
  const int E  = in_sizes[1] / 2;   // 480000
  const int Et = E + N;

  char* p = (char*)d_ws;
  unsigned short* xh = (unsigned short*)p; p += (size_t)N * NH * D * 2;
  unsigned short* xg = (unsigned short*)p; p += (size_t)N * D * 2;
  float* a_s     = (float*)p; p += (size_t)N * NH * 4;
  float* a_d     = (float*)p; p += (size_t)N * NH * 4;
  float* gat_acc = (float*)p; p += (size_t)N * D * 4;
  float* gcn_acc = (float*)p; p += (size_t)N * D * 4;
  float* dinv    = (float*)p; p += (size_t)N * 4;
  int* deg       = (int*)p;   p += (size_t)N * 4;
  int* row_ptr   = (int*)p;   p += (size_t)(N + 1) * 4;
  int* cursor    = (int*)p;   p += (size_t)N * 4;
  int* col_src   = (int*)p;   p += (size_t)Et * 4;
  int* bsum      = (int*)p;   p += 1024;

  hipMemsetAsync(deg, 0, (size_t)N * 4, stream);

  k_gemm<<<(N + 63) / 64, 256, 0, stream>>>(x, Wgat, Wgcn, xh, xg, N);
  k_att<<<N, 256, 0, stream>>>(xh, att_src, att_dst, a_s, a_d, N);
  k_deg<<<(Et + 255) / 256, 256, 0, stream>>>(ei, E, N, deg);
  int nb = (N + 255) / 256;
  k_scan1<<<nb, 256, 0, stream>>>(deg, N, bsum);
  k_scan2<<<1, 128, 0, stream>>>(bsum, nb);
  k_scan3<<<nb, 256, 0, stream>>>(deg, bsum, N, Et, row_ptr, cursor, dinv);
  k_fill<<<(Et + 255) / 256, 256, 0, stream>>>(ei, E, N, cursor, col_src);
  k_agg<<<(N + 3) / 4, 256, 0, stream>>>(xh, xg, a_s, a_d, row_ptr, col_src, dinv,
                                          gat_acc, gcn_acc, N);
  k_final<<<(N + 3) / 4, 256, 0, stream>>>(gat_acc, gcn_acc, b_gat, b_gcn,
                                            W_gate, b_gate, gamma, beta, out, N);
  (void)n_in; (void)out_size; (void)ws_size;
}

// Round 2
// 236.154 us; speedup vs baseline: 1.3185x; 1.3185x over previous
//
#include <hip/hip_runtime.h>
#include <hip/hip_bf16.h>

#define D 128
#define NH 4
#define NEG_SLOPE 0.2f
#define LN_EPS 1e-5f

typedef __attribute__((ext_vector_type(4))) float f32x4;
typedef __attribute__((ext_vector_type(8))) short bf16x8;

__device__ __forceinline__ float bf2f(unsigned short u) {
  union { unsigned int i; float f; } c; c.i = ((unsigned int)u) << 16; return c.f;
}
__device__ __forceinline__ unsigned short f2bf(float f) {
  union { float f; unsigned int i; } c; c.f = f;
  unsigned int r = c.i + 0x7FFFu + ((c.i >> 16) & 1u);  // RNE
  return (unsigned short)(r >> 16);
}

// ---------------- W prep: Wt[c][k] = W'[k][c] in bf16, c = h*128+f | 512+f ----
__global__ __launch_bounds__(128) void k_prep_w(
    const float* __restrict__ Wgat, const float* __restrict__ Wgcn,
    unsigned short* __restrict__ Wt)
{
  int c = blockIdx.x;     // 0..639
  int k = threadIdx.x;    // 0..127
  float v;
  if (c < 512) { int h = c >> 7, f = c & 127; v = Wgat[((size_t)h * D + k) * D + f]; }
  else         { v = Wgcn[(size_t)k * D + (c - 512)]; }
  Wt[(size_t)c * D + k] = f2bf(v);
}

// ---------------- MFMA GEMM: X[30000x128] @ W'[128x640] -> xh, xg (bf16) -------
// grid (235, 10); BM=128, BN=64, K=128 staged fully. XOR-swizzled LDS.
__global__ __launch_bounds__(256) void k_gemm_mfma(
    const float* __restrict__ x, const unsigned short* __restrict__ Wt,
    unsigned short* __restrict__ xh, unsigned short* __restrict__ xg, int N)
{
  __shared__ unsigned short As[128 * 128];  // [row][k], 16B-block kb ^= row&7
  __shared__ unsigned short Bs[64 * 128];   // [col][k], 16B-block kb ^= col&7
  const int t = threadIdx.x;
  const int m0 = blockIdx.x * 128;
  const int c0 = blockIdx.y * 64;

  // stage A: fp32 -> bf16, swizzled
  #pragma unroll
  for (int i = 0; i < 16; ++i) {
    int f = i * 256 + t;          // float4 index
    int row = f >> 5;             // 0..127
    int k4 = (f & 31) * 4;        // 0,4,...,124
    int gm = m0 + row;
    float4 v = (gm < N) ? *(const float4*)&x[(size_t)gm * D + k4]
                        : make_float4(0.f, 0.f, 0.f, 0.f);
    ushort4 b;
    b.x = f2bf(v.x); b.y = f2bf(v.y); b.z = f2bf(v.z); b.w = f2bf(v.w);
    int kb = k4 >> 3, ko = k4 & 7;
    *(ushort4*)&As[row * 128 + ((kb ^ (row & 7)) << 3) + ko] = b;
  }
  // stage B: bf16 16B blocks, swizzled
  #pragma unroll
  for (int i = 0; i < 4; ++i) {
    int g = i * 256 + t;          // 16B-block index
    int col = g >> 4;             // 0..63
    int kb = g & 15;
    uint4 v = *(const uint4*)&Wt[(size_t)(c0 + col) * D + kb * 8];
    *(uint4*)&Bs[col * 128 + ((kb ^ (col & 7)) << 3)] = v;
  }
  __syncthreads();

  const int w = t >> 6, l = t & 63;
  const int wr = w >> 1, wc = w & 1;
  const int lrow = l & 15, lk = l >> 4;

  f32x4 acc[4][2];
  #pragma unroll
  for (int m = 0; m < 4; ++m)
    #pragma unroll
    for (int n = 0; n < 2; ++n) acc[m][n] = (f32x4){0.f, 0.f, 0.f, 0.f};

  #pragma unroll
  for (int ks = 0; ks < 4; ++ks) {
    int kb = ks * 4 + lk;
    bf16x8 a[4], b[2];
    #pragma unroll
    for (int m = 0; m < 4; ++m) {
      int row = wr * 64 + m * 16 + lrow;
      a[m] = *(const bf16x8*)&As[row * 128 + ((kb ^ (row & 7)) << 3)];
    }
    #pragma unroll
    for (int n = 0; n < 2; ++n) {
      int col = wc * 32 + n * 16 + lrow;
      b[n] = *(const bf16x8*)&Bs[col * 128 + ((kb ^ (col & 7)) << 3)];
    }
    #pragma unroll
    for (int m = 0; m < 4; ++m)
      #pragma unroll
      for (int n = 0; n < 2; ++n)
        acc[m][n] = __builtin_amdgcn_mfma_f32_16x16x32_bf16(a[m], b[n], acc[m][n], 0, 0, 0);
  }

  // epilogue: D frag col = lane&15, row = (lane>>4)*4 + j
  const bool is_gat = (c0 < 512);
  const int h = c0 >> 7;
  #pragma unroll
  for (int m = 0; m < 4; ++m) {
    #pragma unroll
    for (int n = 0; n < 2; ++n) {
      int c = c0 + wc * 32 + n * 16 + lrow;
      #pragma unroll
      for (int j = 0; j < 4; ++j) {
        int r = m0 + wr * 64 + m * 16 + lk * 4 + j;
        if (r >= N) continue;
        unsigned short bv = f2bf(acc[m][n][j]);
        if (is_gat) xh[((size_t)r * NH + h) * D + (c & 127)] = bv;
        else        xg[(size_t)r * D + (c - 512)] = bv;
      }
    }
  }
}

// ---------------- per-node attention dots: a_s[n,h], a_d[n,h] -------------------
__global__ __launch_bounds__(256) void k_att(
    const unsigned short* __restrict__ xh,
    const float* __restrict__ att_src, const float* __restrict__ att_dst,
    float* __restrict__ a_s, float* __restrict__ a_d, int N)
{
  int n = blockIdx.x;
  int h = threadIdx.x >> 6;
  int l = threadIdx.x & 63;
  const unsigned short* row = xh + ((size_t)n * NH + h) * D;
  float v0 = bf2f(row[l]), v1 = bf2f(row[l + 64]);
  float s = v0 * att_src[h * D + l] + v1 * att_src[h * D + l + 64];
  float d = v0 * att_dst[h * D + l] + v1 * att_dst[h * D + l + 64];
  #pragma unroll
  for (int off = 32; off; off >>= 1) { s += __shfl_xor(s, off); d += __shfl_xor(d, off); }
  if (l == 0) { a_s[n * NH + h] = s; a_d[n * NH + h] = d; }
}

// ---------------- CSR build ----------------------------------------------------
__global__ void k_deg(const int* __restrict__ ei, int E, int N, int* __restrict__ deg)
{
  int e = blockIdx.x * blockDim.x + threadIdx.x;
  if (e >= E + N) return;
  int dst = (e < E) ? ei[E + e] : (e - E);
  atomicAdd(&deg[dst], 1);
}

__global__ void k_scan1(const int* __restrict__ deg, int N, int* __restrict__ bsum)
{
  __shared__ int s[256];
  int t = threadIdx.x;
  int i = blockIdx.x * 256 + t;
  s[t] = (i < N) ? deg[i] : 0;
  __syncthreads();
  for (int off = 128; off; off >>= 1) {
    if (t < off) s[t] += s[t + off];
    __syncthreads();
  }
  if (t == 0) bsum[blockIdx.x] = s[0];
}

__global__ void k_scan2(int* __restrict__ bsum, int nb)
{
  __shared__ int s[128];
  int t = threadIdx.x;
  int v = (t < nb) ? bsum[t] : 0;
  s[t] = v; __syncthreads();
  for (int off = 1; off < 128; off <<= 1) {
    int xv = (t >= off) ? s[t - off] : 0;
    __syncthreads();
    s[t] += xv;
    __syncthreads();
  }
  if (t < nb) bsum[t] = s[t] - v;   // exclusive
}

__global__ void k_scan3(const int* __restrict__ deg, const int* __restrict__ bsum,
                        int N, int Et, int* __restrict__ row_ptr,
                        int* __restrict__ cursor, float* __restrict__ dinv)
{
  __shared__ int s[256];
  int t = threadIdx.x;
  int i = blockIdx.x * 256 + t;
  int v = (i < N) ? deg[i] : 0;
  s[t] = v; __syncthreads();
  for (int off = 1; off < 256; off <<= 1) {
    int xv = (t >= off) ? s[t - off] : 0;
    __syncthreads();
    s[t] += xv;
    __syncthreads();
  }
  if (i < N) {
    int excl = s[t] - v + bsum[blockIdx.x];
    row_ptr[i] = excl;
    cursor[i] = excl;
    dinv[i] = rsqrtf((float)v);    // deg >= 1 (self-loop)
  }
  if (i == 0) row_ptr[N] = Et;
}

__global__ void k_fill(const int* __restrict__ ei, int E, int N,
                       int* __restrict__ cursor, int* __restrict__ col_src)
{
  int e = blockIdx.x * blockDim.x + threadIdx.x;
  if (e >= E + N) return;
  int src, dst;
  if (e < E) { src = ei[e]; dst = ei[E + e]; }
  else       { src = e - E; dst = src; }
  int pos = atomicAdd(&cursor[dst], 1);
  col_src[pos] = src;
}

// ---------------- aggregation: one wave per node, softmax + GAT + GCN ----------
__global__ __launch_bounds__(256) void k_agg(
    const unsigned short* __restrict__ xh, const unsigned short* __restrict__ xg,
    const float* __restrict__ a_s, const float* __restrict__ a_d,
    const int* __restrict__ row_ptr, const int* __restrict__ col_src,
    const float* __restrict__ dinv,
    float* __restrict__ gat_acc, float* __restrict__ gcn_acc, int N)
{
  int n = blockIdx.x * 4 + (threadIdx.x >> 6);
  if (n >= N) return;
  int l = threadIdx.x & 63;
  int start = row_ptr[n], end = row_ptr[n + 1];
  float4 adn = ((const float4*)a_d)[n];

  // pass 1: softmax denominators (edges parallel over lanes)
  float den0 = 0.f, den1 = 0.f, den2 = 0.f, den3 = 0.f;
  for (int base = start; base < end; base += 64) {
    int e = base + l;
    if (e < end) {
      int s = col_src[e];
      float4 as4 = ((const float4*)a_s)[s];
      float e0 = as4.x + adn.x; e0 = (e0 >= 0.f) ? e0 : NEG_SLOPE * e0;
      float e1 = as4.y + adn.y; e1 = (e1 >= 0.f) ? e1 : NEG_SLOPE * e1;
      float e2 = as4.z + adn.z; e2 = (e2 >= 0.f) ? e2 : NEG_SLOPE * e2;
      float e3 = as4.w + adn.w; e3 = (e3 >= 0.f) ? e3 : NEG_SLOPE * e3;
      den0 += __expf(e0); den1 += __expf(e1);
      den2 += __expf(e2); den3 += __expf(e3);
    }
  }
  #pragma unroll
  for (int off = 32; off; off >>= 1) {
    den0 += __shfl_xor(den0, off); den1 += __shfl_xor(den1, off);
    den2 += __shfl_xor(den2, off); den3 += __shfl_xor(den3, off);
  }
  const float r0 = 1.f / den0, r1 = 1.f / den1, r2 = 1.f / den2, r3 = 1.f / den3;
  const float dn = dinv[n];

  // pass 2: weighted aggregation, lane l owns dims {2l, 2l+1}
  float gx = 0.f, gy = 0.f, cx = 0.f, cy = 0.f;
  const ushort2* xh2 = (const ushort2*)xh;
  const ushort2* xg2 = (const ushort2*)xg;
  for (int e = start; e < end; ++e) {
    int s = col_src[e];
    float4 as4 = ((const float4*)a_s)[s];
    float e0 = as4.x + adn.x; e0 = (e0 >= 0.f) ? e0 : NEG_SLOPE * e0;
    float e1 = as4.y + adn.y; e1 = (e1 >= 0.f) ? e1 : NEG_SLOPE * e1;
    float e2 = as4.z + adn.z; e2 = (e2 >= 0.f) ? e2 : NEG_SLOPE * e2;
    float e3 = as4.w + adn.w; e3 = (e3 >= 0.f) ? e3 : NEG_SLOPE * e3;
    float a0 = __expf(e0) * r0, a1 = __expf(e1) * r1;
    float a2 = __expf(e2) * r2, a3 = __expf(e3) * r3;
    float coef = dn * dinv[s];
    size_t rb = (size_t)s * 256 + l;     // ushort2 index, head stride 64
    ushort2 v0 = xh2[rb];
    ushort2 v1 = xh2[rb + 64];
    ushort2 v2 = xh2[rb + 128];
    ushort2 v3 = xh2[rb + 192];
    gx += a0 * bf2f(v0.x) + a1 * bf2f(v1.x) + a2 * bf2f(v2.x) + a3 * bf2f(v3.x);
    gy += a0 * bf2f(v0.y) + a1 * bf2f(v1.y) + a2 * bf2f(v2.y) + a3 * bf2f(v3.y);
    ushort2 vg = xg2[(size_t)s * 64 + l];
    cx += coef * bf2f(vg.x);
    cy += coef * bf2f(vg.y);
  }
  ((float2*)gat_acc)[(size_t)n * 64 + l] = make_float2(gx, gy);
  ((float2*)gcn_acc)[(size_t)n * 64 + l] = make_float2(cx, cy);
}

// ---------------- gate + residual + LayerNorm ----------------------------------
__global__ __launch_bounds__(256) void k_final(
    const float* __restrict__ gat_acc, const float* __restrict__ gcn_acc,
    const float* __restrict__ b_gat, const float* __restrict__ b_gcn,
    const float* __restrict__ W_gate, const float* __restrict__ b_gate,
    const float* __restrict__ gamma, const float* __restrict__ beta,
    float* __restrict__ out, int N)
{
  int n = blockIdx.x * 4 + (threadIdx.x >> 6);
  if (n >= N) return;
  int l = threadIdx.x & 63;
  float2 ga = ((const float2*)gat_acc)[(size_t)n * 64 + l];
  float2 gc = ((const float2*)gcn_acc)[(size_t)n * 64 + l];
  float2 bg = ((const float2*)b_gat)[l];
  float2 bc = ((const float2*)b_gcn)[l];
  float g0x = ga.x * 0.25f + bg.x, g0y = ga.y * 0.25f + bg.y;
  float c0x = gc.x + bc.x,         c0y = gc.y + bc.y;
  float4 wa = ((const float4*)W_gate)[l];        // rows 2l, 2l+1
  float4 wc = ((const float4*)W_gate)[64 + l];   // rows 128+2l, 128+2l+1
  float z0 = g0x * wa.x + g0y * wa.z + c0x * wc.x + c0y * wc.z;
  float z1 = g0x * wa.y + g0y * wa.w + c0x * wc.y + c0y * wc.w;
  #pragma unroll
  for (int off = 32; off; off >>= 1) { z0 += __shfl_xor(z0, off); z1 += __shfl_xor(z1, off); }
  z0 += b_gate[0]; z1 += b_gate[1];
  float mz = fmaxf(z0, z1);
  float ez0 = __expf(z0 - mz), ez1 = __expf(z1 - mz);
  float inv = 1.f / (ez0 + ez1);
  float w0 = ez0 * inv, w1 = ez1 * inv;
  float hx = (1.f + w0) * g0x + w1 * c0x;   // fused + gat_out
  float hy = (1.f + w0) * g0y + w1 * c0y;
  float ssum = hx + hy;
  #pragma unroll
  for (int off = 32; off; off >>= 1) ssum += __shfl_xor(ssum, off);
  float mu = ssum * (1.f / 128.f);
  float vx = hx - mu, vy = hy - mu;
  float vsum = vx * vx + vy * vy;
  #pragma unroll
  for (int off = 32; off; off >>= 1) vsum += __shfl_xor(vsum, off);
  float rstd = rsqrtf(vsum * (1.f / 128.f) + LN_EPS);
  float2 gm = ((const float2*)gamma)[l];
  float2 bt = ((const float2*)beta)[l];
  float2 o;
  o.x = vx * rstd * gm.x + bt.x;
  o.y = vy * rstd * gm.y + bt.y;
  ((float2*)out)[(size_t)n * 64 + l] = o;
}

extern "C" void kernel_launch(void* const* d_in, const int* in_sizes, int n_in,
                              void* d_out, int out_size, void* d_ws, size_t ws_size,
                              hipStream_t stream)
{
  const float* x       = (const float*)d_in[0];
  const int*   ei      = (const int*)d_in[1];
  const float* Wgat    = (const float*)d_in[2];
  const float* att_src = (const float*)d_in[3];
  const float* att_dst = (const float*)d_in[4];
  const float* b_gat   = (const float*)d_in[5];
  const float* Wgcn    = (const float*)d_in[6];
  const float* b_gcn   = (const float*)d_in[7];
  const float* W_gate  = (const float*)d_in[8];
  const float* b_gate  = (const float*)d_in[9];
  const float* gamma   = (const float*)d_in[10];
  const float* beta    = (const float*)d_in[11];
  float* out = (float*)d_out;

  const int N  = in_sizes[0] / D;   // 30000
  const int E  = in_sizes[1] / 2;   // 480000
  const int Et = E + N;

  char* p = (char*)d_ws;
  unsigned short* xh = (unsigned short*)p; p += (size_t)N * NH * D * 2;
  unsigned short* xg = (unsigned short*)p; p += (size_t)N * D * 2;
  unsigned short* Wt = (unsigned short*)p; p += (size_t)640 * D * 2;
  float* a_s     = (float*)p; p += (size_t)N * NH * 4;
  float* a_d     = (float*)p; p += (size_t)N * NH * 4;
  float* gat_acc = (float*)p; p += (size_t)N * D * 4;
  float* gcn_acc = (float*)p; p += (size_t)N * D * 4;
  float* dinv    = (float*)p; p += (size_t)N * 4;
  int* deg       = (int*)p;   p += (size_t)N * 4;
  int* row_ptr   = (int*)p;   p += (size_t)(N + 1) * 4;
  int* cursor    = (int*)p;   p += (size_t)N * 4;
  int* col_src   = (int*)p;   p += (size_t)Et * 4;
  int* bsum      = (int*)p;   p += 1024;

  hipMemsetAsync(deg, 0, (size_t)N * 4, stream);

  k_prep_w<<<640, 128, 0, stream>>>(Wgat, Wgcn, Wt);
  dim3 gg((N + 127) / 128, 10);
  k_gemm_mfma<<<gg, 256, 0, stream>>>(x, Wt, xh, xg, N);
  k_att<<<N, 256, 0, stream>>>(xh, att_src, att_dst, a_s, a_d, N);
  k_deg<<<(Et + 255) / 256, 256, 0, stream>>>(ei, E, N, deg);
  int nb = (N + 255) / 256;
  k_scan1<<<nb, 256, 0, stream>>>(deg, N, bsum);
  k_scan2<<<1, 128, 0, stream>>>(bsum, nb);
  k_scan3<<<nb, 256, 0, stream>>>(deg, bsum, N, Et, row_ptr, cursor, dinv);
  k_fill<<<(Et + 255) / 256, 256, 0, stream>>>(ei, E, N, cursor, col_src);
  k_agg<<<(N + 3) / 4, 256, 0, stream>>>(xh, xg, a_s, a_d, row_ptr, col_src, dinv,
                                          gat_acc, gcn_acc, N);
  k_final<<<(N + 3) / 4, 256, 0, stream>>>(gat_acc, gcn_acc, b_gat, b_gcn,
                                            W_gate, b_gate, gamma, beta, out, N);
  (void)n_in; (void)out_size; (void)ws_size;
}

// Round 3
// 227.406 us; speedup vs baseline: 1.3692x; 1.0385x over previous
//
#include <hip/hip_runtime.h>
#include <hip/hip_bf16.h>

#define D 128
#define NH 4
#define NEG_SLOPE 0.2f
#define LN_EPS 1e-5f

typedef __attribute__((ext_vector_type(4))) float f32x4;
typedef __attribute__((ext_vector_type(8))) short bf16x8;

__device__ __forceinline__ float bf2f(unsigned short u) {
  union { unsigned int i; float f; } c; c.i = ((unsigned int)u) << 16; return c.f;
}
__device__ __forceinline__ float bflo(unsigned int u) {
  union { unsigned int i; float f; } c; c.i = u << 16; return c.f;
}
__device__ __forceinline__ float bfhi(unsigned int u) {
  union { unsigned int i; float f; } c; c.i = u & 0xFFFF0000u; return c.f;
}
__device__ __forceinline__ unsigned short f2bf(float f) {
  union { float f; unsigned int i; } c; c.f = f;
  unsigned int r = c.i + 0x7FFFu + ((c.i >> 16) & 1u);  // RNE
  return (unsigned short)(r >> 16);
}

// ---------------- W prep: Wt[c][k] = W'[k][c] in bf16, c = h*128+f | 512+f ----
__global__ __launch_bounds__(128) void k_prep_w(
    const float* __restrict__ Wgat, const float* __restrict__ Wgcn,
    unsigned short* __restrict__ Wt)
{
  int c = blockIdx.x;     // 0..639
  int k = threadIdx.x;    // 0..127
  float v;
  if (c < 512) { int h = c >> 7, f = c & 127; v = Wgat[((size_t)h * D + k) * D + f]; }
  else         { v = Wgcn[(size_t)k * D + (c - 512)]; }
  Wt[(size_t)c * D + k] = f2bf(v);
}

// ---------------- MFMA GEMM: X[30000x128] @ W'[128x640] -------------------------
// xh interleaved [n][d][h] bf16; xg [n][d] bf16. grid (235, 10).
__global__ __launch_bounds__(256) void k_gemm_mfma(
    const float* __restrict__ x, const unsigned short* __restrict__ Wt,
    unsigned short* __restrict__ xh, unsigned short* __restrict__ xg, int N)
{
  __shared__ unsigned short As[128 * 128];  // [row][k], 16B-block kb ^= row&7
  __shared__ unsigned short Bs[64 * 128];   // [col][k], 16B-block kb ^= col&7
  const int t = threadIdx.x;
  const int m0 = blockIdx.x * 128;
  const int c0 = blockIdx.y * 64;

  #pragma unroll
  for (int i = 0; i < 16; ++i) {
    int f = i * 256 + t;          // float4 index
    int row = f >> 5;             // 0..127
    int k4 = (f & 31) * 4;        // 0,4,...,124
    int gm = m0 + row;
    float4 v = (gm < N) ? *(const float4*)&x[(size_t)gm * D + k4]
                        : make_float4(0.f, 0.f, 0.f, 0.f);
    ushort4 b;
    b.x = f2bf(v.x); b.y = f2bf(v.y); b.z = f2bf(v.z); b.w = f2bf(v.w);
    int kb = k4 >> 3, ko = k4 & 7;
    *(ushort4*)&As[row * 128 + ((kb ^ (row & 7)) << 3) + ko] = b;
  }
  #pragma unroll
  for (int i = 0; i < 4; ++i) {
    int g = i * 256 + t;          // 16B-block index
    int col = g >> 4;             // 0..63
    int kb = g & 15;
    uint4 v = *(const uint4*)&Wt[(size_t)(c0 + col) * D + kb * 8];
    *(uint4*)&Bs[col * 128 + ((kb ^ (col & 7)) << 3)] = v;
  }
  __syncthreads();

  const int w = t >> 6, l = t & 63;
  const int wr = w >> 1, wc = w & 1;
  const int lrow = l & 15, lk = l >> 4;

  f32x4 acc[4][2];
  #pragma unroll
  for (int m = 0; m < 4; ++m)
    #pragma unroll
    for (int n = 0; n < 2; ++n) acc[m][n] = (f32x4){0.f, 0.f, 0.f, 0.f};

  #pragma unroll
  for (int ks = 0; ks < 4; ++ks) {
    int kb = ks * 4 + lk;
    bf16x8 a[4], b[2];
    #pragma unroll
    for (int m = 0; m < 4; ++m) {
      int row = wr * 64 + m * 16 + lrow;
      a[m] = *(const bf16x8*)&As[row * 128 + ((kb ^ (row & 7)) << 3)];
    }
    #pragma unroll
    for (int n = 0; n < 2; ++n) {
      int col = wc * 32 + n * 16 + lrow;
      b[n] = *(const bf16x8*)&Bs[col * 128 + ((kb ^ (col & 7)) << 3)];
    }
    #pragma unroll
    for (int m = 0; m < 4; ++m)
      #pragma unroll
      for (int n = 0; n < 2; ++n)
        acc[m][n] = __builtin_amdgcn_mfma_f32_16x16x32_bf16(a[m], b[n], acc[m][n], 0, 0, 0);
  }

  const bool is_gat = (c0 < 512);
  const int h = c0 >> 7;
  #pragma unroll
  for (int m = 0; m < 4; ++m) {
    #pragma unroll
    for (int n = 0; n < 2; ++n) {
      int c = c0 + wc * 32 + n * 16 + lrow;
      #pragma unroll
      for (int j = 0; j < 4; ++j) {
        int r = m0 + wr * 64 + m * 16 + lk * 4 + j;
        if (r >= N) continue;
        unsigned short bv = f2bf(acc[m][n][j]);
        if (is_gat) xh[((size_t)r * D + (c & 127)) * NH + h] = bv;
        else        xg[(size_t)r * D + (c - 512)] = bv;
      }
    }
  }
}

// ---------------- per-node attention dots from interleaved xh -------------------
__global__ __launch_bounds__(256) void k_att(
    const unsigned short* __restrict__ xh,
    const float* __restrict__ att_src, const float* __restrict__ att_dst,
    float* __restrict__ a_s, float* __restrict__ a_d, int N)
{
  const int w = threadIdx.x >> 6, l = threadIdx.x & 63;
  const int n = blockIdx.x * 4 + w;
  if (n >= N) return;
  const uint4 v = *(const uint4*)(xh + ((size_t)n << 9) + (l << 3)); // dims 2l,2l+1
  float x00 = bflo(v.x), x01 = bfhi(v.x), x02 = bflo(v.y), x03 = bfhi(v.y);
  float x10 = bflo(v.z), x11 = bfhi(v.z), x12 = bflo(v.w), x13 = bfhi(v.w);
  float2 as0 = ((const float2*)(att_src))[l];
  float2 as1 = ((const float2*)(att_src + D))[l];
  float2 as2 = ((const float2*)(att_src + 2 * D))[l];
  float2 as3 = ((const float2*)(att_src + 3 * D))[l];
  float2 ad0 = ((const float2*)(att_dst))[l];
  float2 ad1 = ((const float2*)(att_dst + D))[l];
  float2 ad2 = ((const float2*)(att_dst + 2 * D))[l];
  float2 ad3 = ((const float2*)(att_dst + 3 * D))[l];
  float s0 = x00 * as0.x + x10 * as0.y;
  float s1 = x01 * as1.x + x11 * as1.y;
  float s2 = x02 * as2.x + x12 * as2.y;
  float s3 = x03 * as3.x + x13 * as3.y;
  float d0 = x00 * ad0.x + x10 * ad0.y;
  float d1 = x01 * ad1.x + x11 * ad1.y;
  float d2 = x02 * ad2.x + x12 * ad2.y;
  float d3 = x03 * ad3.x + x13 * ad3.y;
  #pragma unroll
  for (int off = 32; off; off >>= 1) {
    s0 += __shfl_xor(s0, off); s1 += __shfl_xor(s1, off);
    s2 += __shfl_xor(s2, off); s3 += __shfl_xor(s3, off);
    d0 += __shfl_xor(d0, off); d1 += __shfl_xor(d1, off);
    d2 += __shfl_xor(d2, off); d3 += __shfl_xor(d3, off);
  }
  if (l == 0) {
    ((float4*)a_s)[n] = make_float4(s0, s1, s2, s3);
    ((float4*)a_d)[n] = make_float4(d0, d1, d2, d3);
  }
}

// ---------------- CSR build ----------------------------------------------------
__global__ void k_deg(const int* __restrict__ ei, int E, int N, int* __restrict__ deg)
{
  int e = blockIdx.x * blockDim.x + threadIdx.x;
  if (e >= E + N) return;
  int dst = (e < E) ? ei[E + e] : (e - E);
  atomicAdd(&deg[dst], 1);
}

__global__ void k_scan1(const int* __restrict__ deg, int N, int* __restrict__ bsum)
{
  __shared__ int s[256];
  int t = threadIdx.x;
  int i = blockIdx.x * 256 + t;
  s[t] = (i < N) ? deg[i] : 0;
  __syncthreads();
  for (int off = 128; off; off >>= 1) {
    if (t < off) s[t] += s[t + off];
    __syncthreads();
  }
  if (t == 0) bsum[blockIdx.x] = s[0];
}

__global__ void k_scan2(int* __restrict__ bsum, int nb)
{
  __shared__ int s[128];
  int t = threadIdx.x;
  int v = (t < nb) ? bsum[t] : 0;
  s[t] = v; __syncthreads();
  for (int off = 1; off < 128; off <<= 1) {
    int xv = (t >= off) ? s[t - off] : 0;
    __syncthreads();
    s[t] += xv;
    __syncthreads();
  }
  if (t < nb) bsum[t] = s[t] - v;   // exclusive
}

__global__ void k_scan3(const int* __restrict__ deg, const int* __restrict__ bsum,
                        int N, int Et, int* __restrict__ row_ptr,
                        int* __restrict__ cursor, float* __restrict__ dinv)
{
  __shared__ int s[256];
  int t = threadIdx.x;
  int i = blockIdx.x * 256 + t;
  int v = (i < N) ? deg[i] : 0;
  s[t] = v; __syncthreads();
  for (int off = 1; off < 256; off <<= 1) {
    int xv = (t >= off) ? s[t - off] : 0;
    __syncthreads();
    s[t] += xv;
    __syncthreads();
  }
  if (i < N) {
    int excl = s[t] - v + bsum[blockIdx.x];
    row_ptr[i] = excl;
    cursor[i] = excl;
    dinv[i] = rsqrtf((float)v);    // deg >= 1 (self-loop)
  }
  if (i == 0) row_ptr[N] = Et;
}

__global__ void k_fill(const int* __restrict__ ei, int E, int N,
                       int* __restrict__ cursor, int* __restrict__ col_src)
{
  int e = blockIdx.x * blockDim.x + threadIdx.x;
  if (e >= E + N) return;
  int src, dst;
  if (e < E) { src = ei[e]; dst = ei[E + e]; }
  else       { src = e - E; dst = src; }
  int pos = atomicAdd(&cursor[dst], 1);
  col_src[pos] = src;
}

// ---------------- single-pass aggregation + gate + LayerNorm --------------------
// one wave per node; 64-edge chunks: phase A computes exps -> wave-private LDS,
// phase B accumulates per-head (normalization deferred to the end).
__global__ __launch_bounds__(256) void k_agg(
    const unsigned short* __restrict__ xh, const unsigned short* __restrict__ xg,
    const float* __restrict__ a_s, const float* __restrict__ a_d,
    const int* __restrict__ row_ptr, const int* __restrict__ col_src,
    const float* __restrict__ dinv,
    const float* __restrict__ b_gat, const float* __restrict__ b_gcn,
    const float* __restrict__ W_gate, const float* __restrict__ b_gate,
    const float* __restrict__ gamma, const float* __restrict__ beta,
    float* __restrict__ out, int N)
{
  __shared__ float4 sh_al[4][64];
  __shared__ int    sh_src[4][64];
  __shared__ float  sh_cf[4][64];
  const int w = threadIdx.x >> 6, l = threadIdx.x & 63;
  const int n = blockIdx.x * 4 + w;
  if (n >= N) return;
  const int start = row_ptr[n], end = row_ptr[n + 1];
  const float4 adn = ((const float4*)a_d)[n];

  float den0 = 0.f, den1 = 0.f, den2 = 0.f, den3 = 0.f;
  float g0x = 0.f, g1x = 0.f, g2x = 0.f, g3x = 0.f;
  float g0y = 0.f, g1y = 0.f, g2y = 0.f, g3y = 0.f;
  float cx = 0.f, cy = 0.f;

  for (int base = start; base < end; base += 64) {
    const int cnt = min(64, end - base);
    if (l < cnt) {
      int s = col_src[base + l];
      float4 as4 = ((const float4*)a_s)[s];
      float e0 = as4.x + adn.x; e0 = (e0 >= 0.f) ? e0 : NEG_SLOPE * e0;
      float e1 = as4.y + adn.y; e1 = (e1 >= 0.f) ? e1 : NEG_SLOPE * e1;
      float e2 = as4.z + adn.z; e2 = (e2 >= 0.f) ? e2 : NEG_SLOPE * e2;
      float e3 = as4.w + adn.w; e3 = (e3 >= 0.f) ? e3 : NEG_SLOPE * e3;
      float x0 = __expf(e0), x1 = __expf(e1), x2 = __expf(e2), x3 = __expf(e3);
      den0 += x0; den1 += x1; den2 += x2; den3 += x3;
      sh_al[w][l] = make_float4(x0, x1, x2, x3);
      sh_src[w][l] = s;
      sh_cf[w][l] = dinv[s];
    }
    for (int j = 0; j < cnt; ++j) {
      float4 al = sh_al[w][j];
      int s = sh_src[w][j];
      float cf = sh_cf[w][j];
      const uint4 v = *(const uint4*)(xh + ((size_t)s << 9) + (l << 3));
      g0x += al.x * bflo(v.x); g1x += al.y * bfhi(v.x);
      g2x += al.z * bflo(v.y); g3x += al.w * bfhi(v.y);
      g0y += al.x * bflo(v.z); g1y += al.y * bfhi(v.z);
      g2y += al.z * bflo(v.w); g3y += al.w * bfhi(v.w);
      unsigned int gv = *(const unsigned int*)(xg + ((size_t)s << 7) + (l << 1));
      cx += cf * bflo(gv); cy += cf * bfhi(gv);
    }
  }

  #pragma unroll
  for (int off = 32; off; off >>= 1) {
    den0 += __shfl_xor(den0, off); den1 += __shfl_xor(den1, off);
    den2 += __shfl_xor(den2, off); den3 += __shfl_xor(den3, off);
  }
  const float r0 = 1.f / den0, r1 = 1.f / den1, r2 = 1.f / den2, r3 = 1.f / den3;
  float gx = g0x * r0 + g1x * r1 + g2x * r2 + g3x * r3;
  float gy = g0y * r0 + g1y * r1 + g2y * r2 + g3y * r3;
  const float dn = dinv[n];
  cx *= dn; cy *= dn;

  // gate + residual + LayerNorm (lane l owns dims 2l, 2l+1)
  float2 bg = ((const float2*)b_gat)[l];
  float2 bc = ((const float2*)b_gcn)[l];
  float gax = gx * 0.25f + bg.x, gay = gy * 0.25f + bg.y;
  float c0x = cx + bc.x, c0y = cy + bc.y;
  float4 wa = ((const float4*)W_gate)[l];
  float4 wc = ((const float4*)W_gate)[64 + l];
  float z0 = gax * wa.x + gay * wa.z + c0x * wc.x + c0y * wc.z;
  float z1 = gax * wa.y + gay * wa.w + c0x * wc.y + c0y * wc.w;
  #pragma unroll
  for (int off = 32; off; off >>= 1) { z0 += __shfl_xor(z0, off); z1 += __shfl_xor(z1, off); }
  z0 += b_gate[0]; z1 += b_gate[1];
  float mz = fmaxf(z0, z1);
  float ez0 = __expf(z0 - mz), ez1 = __expf(z1 - mz);
  float inv = 1.f / (ez0 + ez1);
  float w0 = ez0 * inv, w1 = ez1 * inv;
  float hx = (1.f + w0) * gax + w1 * c0x;
  float hy = (1.f + w0) * gay + w1 * c0y;
  float ssum = hx + hy;
  #pragma unroll
  for (int off = 32; off; off >>= 1) ssum += __shfl_xor(ssum, off);
  float mu = ssum * (1.f / 128.f);
  float vx = hx - mu, vy = hy - mu;
  float vsum = vx * vx + vy * vy;
  #pragma unroll
  for (int off = 32; off; off >>= 1) vsum += __shfl_xor(vsum, off);
  float rstd = rsqrtf(vsum * (1.f / 128.f) + LN_EPS);
  float2 gm = ((const float2*)gamma)[l];
  float2 bt = ((const float2*)beta)[l];
  float2 o;
  o.x = vx * rstd * gm.x + bt.x;
  o.y = vy * rstd * gm.y + bt.y;
  ((float2*)out)[(size_t)n * 64 + l] = o;
}

extern "C" void kernel_launch(void* const* d_in, const int* in_sizes, int n_in,
                              void* d_out, int out_size, void* d_ws, size_t ws_size,
                              hipStream_t stream)
{
  const float* x       = (const float*)d_in[0];
  const int*   ei      = (const int*)d_in[1];
  const float* Wgat    = (const float*)d_in[2];
  const float* att_src = (const float*)d_in[3];
  const float* att_dst = (const float*)d_in[4];
  const float* b_gat   = (const float*)d_in[5];
  const float* Wgcn    = (const float*)d_in[6];
  const float* b_gcn   = (const float*)d_in[7];
  const float* W_gate  = (const float*)d_in[8];
  const float* b_gate  = (const float*)d_in[9];
  const float* gamma   = (const float*)d_in[10];
  const float* beta    = (const float*)d_in[11];
  float* out = (float*)d_out;

  const int N  = in_sizes[0] / D;   // 30000
  const int E  = in_sizes[1] / 2;   // 480000
  const int Et = E + N;

  char* p = (char*)d_ws;
  unsigned short* xh = (unsigned short*)p; p += (size_t)N * NH * D * 2;  // [n][d][h]
  unsigned short* xg = (unsigned short*)p; p += (size_t)N * D * 2;       // [n][d]
  unsigned short* Wt = (unsigned short*)p; p += (size_t)640 * D * 2;
  float* a_s     = (float*)p; p += (size_t)N * NH * 4;
  float* a_d     = (float*)p; p += (size_t)N * NH * 4;
  float* dinv    = (float*)p; p += (size_t)N * 4;
  int* deg       = (int*)p;   p += (size_t)N * 4;
  int* row_ptr   = (int*)p;   p += (size_t)(N + 1) * 4;
  int* cursor    = (int*)p;   p += (size_t)N * 4;
  int* col_src   = (int*)p;   p += (size_t)Et * 4;
  int* bsum      = (int*)p;   p += 1024;

  hipMemsetAsync(deg, 0, (size_t)N * 4, stream);

  k_prep_w<<<640, 128, 0, stream>>>(Wgat, Wgcn, Wt);
  dim3 gg((N + 127) / 128, 10);
  k_gemm_mfma<<<gg, 256, 0, stream>>>(x, Wt, xh, xg, N);
  k_att<<<(N + 3) / 4, 256, 0, stream>>>(xh, att_src, att_dst, a_s, a_d, N);
  k_deg<<<(Et + 255) / 256, 256, 0, stream>>>(ei, E, N, deg);
  int nb = (N + 255) / 256;
  k_scan1<<<nb, 256, 0, stream>>>(deg, N, bsum);
  k_scan2<<<1, 128, 0, stream>>>(bsum, nb);
  k_scan3<<<nb, 256, 0, stream>>>(deg, bsum, N, Et, row_ptr, cursor, dinv);
  k_fill<<<(Et + 255) / 256, 256, 0, stream>>>(ei, E, N, cursor, col_src);
  k_agg<<<(N + 3) / 4, 256, 0, stream>>>(xh, xg, a_s, a_d, row_ptr, col_src, dinv,
                                          b_gat, b_gcn, W_gate, b_gate, gamma, beta,
                                          out, N);
  (void)n_in; (void)out_size; (void)ws_size;
}